// Round 1
// baseline (527.522 us; speedup 1.0000x reference)
//
#include <hip/hip_runtime.h>

#define L 2048
#define D 2048
#define NH 16
#define HD 128

typedef __attribute__((ext_vector_type(8))) _Float16 half8;
typedef __attribute__((ext_vector_type(4))) float f32x4;

// ---------------- f32 -> fp16 convert ----------------
__global__ void cvt_kernel(const float* __restrict__ in, _Float16* __restrict__ out, int n4) {
    int idx = blockIdx.x * blockDim.x + threadIdx.x;
    int stride = gridDim.x * blockDim.x;
    for (int i = idx; i < n4; i += stride) {
        float4 v = reinterpret_cast<const float4*>(in)[i];
        union { _Float16 h[4]; uint2 u; } pk;
        pk.h[0] = (_Float16)v.x; pk.h[1] = (_Float16)v.y;
        pk.h[2] = (_Float16)v.z; pk.h[3] = (_Float16)v.w;
        reinterpret_cast<uint2*>(out)[i] = pk.u;
    }
}

// ---------------- NT GEMM: C[M][N] = A[M][K] * B[N][K]^T ----------------
// EPI 0: scatter qkv -> qk[t][h][l][d] (t<2) and vt[h][d][l] (t==2), fp16
// EPI 1: write f32 C row-major to Cout
template <int EPI>
__global__ __launch_bounds__(256) void gemm_nt(
    const _Float16* __restrict__ A, const _Float16* __restrict__ B,
    float* __restrict__ Cout, _Float16* __restrict__ qk, _Float16* __restrict__ vt,
    int M, int N, int K)
{
    int wid = threadIdx.x >> 6;
    int lane = threadIdx.x & 63;
    int wr = wid >> 1, wc = wid & 1;
    int m0 = blockIdx.x * 128 + wr * 64;
    int n0 = blockIdx.y * 128 + wc * 64;
    int lr = lane & 15;   // row/col within 16
    int lg = lane >> 4;   // group 0..3

    f32x4 acc[4][4];
#pragma unroll
    for (int i = 0; i < 4; i++)
#pragma unroll
        for (int j = 0; j < 4; j++)
            acc[i][j] = (f32x4){0.f, 0.f, 0.f, 0.f};

    for (int k0 = 0; k0 < K; k0 += 32) {
        int ko = k0 + lg * 8;
        half8 a[4], b[4];
#pragma unroll
        for (int i = 0; i < 4; i++)
            a[i] = *reinterpret_cast<const half8*>(A + (size_t)(m0 + i * 16 + lr) * K + ko);
#pragma unroll
        for (int j = 0; j < 4; j++)
            b[j] = *reinterpret_cast<const half8*>(B + (size_t)(n0 + j * 16 + lr) * K + ko);
#pragma unroll
        for (int i = 0; i < 4; i++)
#pragma unroll
            for (int j = 0; j < 4; j++)
                acc[i][j] = __builtin_amdgcn_mfma_f32_16x16x32_f16(a[i], b[j], acc[i][j], 0, 0, 0);
    }

#pragma unroll
    for (int i = 0; i < 4; i++) {
#pragma unroll
        for (int j = 0; j < 4; j++) {
#pragma unroll
            for (int r = 0; r < 4; r++) {
                int row = m0 + i * 16 + lg * 4 + r;  // C layout: row=(lane>>4)*4+reg
                int col = n0 + j * 16 + lr;          //           col=lane&15
                float v = acc[i][j][r];
                if (EPI == 0) {
                    int t = col >> 11;
                    int w2 = col & 2047;
                    int h = w2 >> 7, d = w2 & 127;
                    if (t < 2) {
                        qk[(((size_t)t * NH + h) * L + row) * HD + d] = (_Float16)v;
                    } else {
                        vt[((size_t)h * HD + d) * L + row] = (_Float16)v;
                    }
                } else {
                    Cout[(size_t)row * N + col] = v;
                }
            }
        }
    }
}

// ---------------- fused RMSNorm + RoPE on q and k planes (in place) ----------------
__global__ void norm_rope(_Float16* __restrict__ qk) {
    int wid = threadIdx.x >> 6, lane = threadIdx.x & 63;
    int row = blockIdx.x * 4 + wid;      // 0 .. 2*NH*L-1
    int l = row & (L - 1);
    int th = row >> 11;                  // t*NH + h, 0..31
    _Float16* p = qk + ((size_t)th * L + l) * HD + lane * 2;
    float x0 = (float)p[0];
    float x1 = (float)p[1];
    float ss = x0 * x0 + x1 * x1;
#pragma unroll
    for (int off = 1; off < 64; off <<= 1) ss += __shfl_xor(ss, off);
    float r = rsqrtf(ss * (1.0f / 128.0f) + 1e-5f);
    float n0 = x0 * r, n1 = x1 * r;
    // RoPE pair index i = lane, angle = l * base^(-2i/128)
    float freq = expf(-(float)(2 * lane) * (1.0f / 128.0f) * logf(100000.0f));
    float ang = (float)l * freq;
    float s, c;
    sincosf(ang, &s, &c);
    // out[2i] = t[2i+1]*cos - t[2i]*sin ; out[2i+1] = t[2i+1]*sin + t[2i]*cos
    p[0] = (_Float16)(n1 * c - n0 * s);
    p[1] = (_Float16)(n1 * s + n0 * c);
}

// ---------------- causal flash attention ----------------
// grid (L/64, NH), block 256 (4 waves). Wave w owns q rows q0 = bx*64 + w*16.
__global__ __launch_bounds__(256) void attn_kernel(
    const _Float16* __restrict__ qk, const _Float16* __restrict__ vt,
    _Float16* __restrict__ out)
{
    __shared__ __align__(16) _Float16 plds[4][16][32];
    int wid = threadIdx.x >> 6, lane = threadIdx.x & 63;
    int h = blockIdx.y;
    int q0 = blockIdx.x * 64 + wid * 16;
    int lr = lane & 15, lg = lane >> 4;

    const _Float16* qn = qk + (size_t)h * L * HD;              // q plane, head h
    const _Float16* kn = qk + ((size_t)(NH + h) * L) * HD;     // k plane, head h
    const _Float16* vp = vt + (size_t)h * HD * L;              // v^T plane, head h

    half8 qa[4];
#pragma unroll
    for (int kk = 0; kk < 4; kk++)
        qa[kk] = *reinterpret_cast<const half8*>(qn + (size_t)(q0 + lr) * HD + kk * 32 + lg * 8);

    f32x4 oacc[8];
#pragma unroll
    for (int jo = 0; jo < 8; jo++) oacc[jo] = (f32x4){0.f, 0.f, 0.f, 0.f};
    float m_r[4], l_r[4];
#pragma unroll
    for (int r = 0; r < 4; r++) { m_r[r] = -__builtin_inff(); l_r[r] = 0.0f; }

    const float scale = 0.08838834764831845f;  // 1/sqrt(128)
    int ntiles = (q0 + 15) / 32 + 1;

    for (int t = 0; t < ntiles; t++) {
        int kv0 = t * 32;
        // S = Q K^T for this 16x32 tile
        f32x4 sC[2];
        sC[0] = (f32x4){0.f, 0.f, 0.f, 0.f};
        sC[1] = (f32x4){0.f, 0.f, 0.f, 0.f};
#pragma unroll
        for (int kk = 0; kk < 4; kk++) {
#pragma unroll
            for (int jt = 0; jt < 2; jt++) {
                half8 bk = *reinterpret_cast<const half8*>(
                    kn + (size_t)(kv0 + jt * 16 + lr) * HD + kk * 32 + lg * 8);
                sC[jt] = __builtin_amdgcn_mfma_f32_16x16x32_f16(qa[kk], bk, sC[jt], 0, 0, 0);
            }
        }
        // online softmax per q-row (each row lives in one 16-lane group, reg r)
        float p0s[4], p1s[4];
#pragma unroll
        for (int r = 0; r < 4; r++) {
            int qrow = q0 + lg * 4 + r;
            float s0 = sC[0][r] * scale;
            float s1 = sC[1][r] * scale;
            if (kv0 + lr > qrow) s0 = -__builtin_inff();
            if (kv0 + 16 + lr > qrow) s1 = -__builtin_inff();
            float mx = fmaxf(s0, s1);
#pragma unroll
            for (int off = 1; off < 16; off <<= 1) mx = fmaxf(mx, __shfl_xor(mx, off));
            float mnew = fmaxf(m_r[r], mx);
            float p0 = __expf(s0 - mnew);
            float p1 = __expf(s1 - mnew);
            float sum = p0 + p1;
#pragma unroll
            for (int off = 1; off < 16; off <<= 1) sum += __shfl_xor(sum, off);
            float corr = __expf(m_r[r] - mnew);
            l_r[r] = l_r[r] * corr + sum;
            m_r[r] = mnew;
#pragma unroll
            for (int jo = 0; jo < 8; jo++) oacc[jo][r] *= corr;
            p0s[r] = p0; p1s[r] = p1;
        }
        // P (C layout) -> LDS -> A-fragment layout (wave-private, same-wave LDS order)
#pragma unroll
        for (int r = 0; r < 4; r++) {
            plds[wid][lg * 4 + r][lr] = (_Float16)p0s[r];
            plds[wid][lg * 4 + r][16 + lr] = (_Float16)p1s[r];
        }
        half8 pa = *reinterpret_cast<const half8*>(&plds[wid][lr][lg * 8]);
        // O += P V
#pragma unroll
        for (int jo = 0; jo < 8; jo++) {
            half8 bv = *reinterpret_cast<const half8*>(
                vp + (size_t)(jo * 16 + lr) * L + kv0 + lg * 8);
            oacc[jo] = __builtin_amdgcn_mfma_f32_16x16x32_f16(pa, bv, oacc[jo], 0, 0, 0);
        }
    }

    // epilogue: O /= l, store fp16 to [l][h*128+d]
#pragma unroll
    for (int jo = 0; jo < 8; jo++) {
#pragma unroll
        for (int r = 0; r < 4; r++) {
            int row = q0 + lg * 4 + r;
            int col = h * HD + jo * 16 + lr;
            out[(size_t)row * D + col] = (_Float16)(oacc[jo][r] / l_r[r]);
        }
    }
}

extern "C" void kernel_launch(void* const* d_in, const int* in_sizes, int n_in,
                              void* d_out, int out_size, void* d_ws, size_t ws_size,
                              hipStream_t stream) {
    const float* x = (const float*)d_in[0];
    const float* wqkv = (const float*)d_in[1];
    const float* wout = (const float*)d_in[2];
    // block_mask (d_in[3]) is tril(ones) == causal; handled analytically.

    _Float16* ws = (_Float16*)d_ws;
    _Float16* xh = ws;                                    // L*D
    _Float16* wqkvh = xh + (size_t)L * D;                 // 3*D*D
    _Float16* wouth = wqkvh + (size_t)3 * D * D;          // D*D
    _Float16* qkh = wouth + (size_t)D * D;                // 2*NH*L*HD
    _Float16* vth = qkh + (size_t)2 * NH * L * HD;        // NH*HD*L
    _Float16* aoh = vth + (size_t)NH * HD * L;            // L*D
    // total 37,748,736 fp16 = 72 MB of d_ws

    cvt_kernel<<<2048, 256, 0, stream>>>(x, xh, L * D / 4);
    cvt_kernel<<<2048, 256, 0, stream>>>(wqkv, wqkvh, 3 * D * D / 4);
    cvt_kernel<<<2048, 256, 0, stream>>>(wout, wouth, D * D / 4);

    gemm_nt<0><<<dim3(L / 128, 3 * D / 128), 256, 0, stream>>>(
        xh, wqkvh, nullptr, qkh, vth, L, 3 * D, D);

    norm_rope<<<2 * NH * L / 4, 256, 0, stream>>>(qkh);

    attn_kernel<<<dim3(L / 64, NH), 256, 0, stream>>>(qkh, vth, aoh);

    gemm_nt<1><<<dim3(L / 128, D / 128), 256, 0, stream>>>(
        aoh, wouth, (float*)d_out, nullptr, nullptr, L, D, D);
}